// Round 1
// baseline (518.721 us; speedup 1.0000x reference)
//
#include <hip/hip_runtime.h>
#include <hip/hip_fp16.h>

#define ROI 5
#define NPTS 25          // 5*5
#define CCH 256
#define HH 135
#define WW 240
#define HWP (HH * WW)    // 32400
#define NV4 (HWP / 4)    // 8100 float4 per plane
#define NB 8
#define NN 1024
#define PER_B (NN * NPTS)        // 25600 records per batch
#define RECN (NB * PER_B)        // 204800 records total

// workspace layout (all 16B-aligned chain):
//   float4  wts [RECN]  @ 0          (3,276,800 B)
//   ushort4 offs[RECN]  @ WS_OFFS    (1,638,400 B)  -- BYTE offsets into fp16 plane
//   int     ooff[RECN]  @ WS_OOFF    (  819,200 B)  -- n*6400 + p
#define WS_WTS  0
#define WS_OFFS (RECN * 16)
#define WS_OOFF (WS_OFFS + RECN * 8)
#define WS_NEED (size_t)(WS_OOFF + RECN * 4)   // 5,734,400 B

// ---------------------------------------------------------------------------
// Phase 1: one record per (b, n, p). Sampling math done ONCE instead of 256x
// (once per channel). ~205K threads, trivially cheap.
// ---------------------------------------------------------------------------
__global__ __launch_bounds__(256) void make_records(const float* __restrict__ cand,
                                                    float4* __restrict__ wts,
                                                    ushort4* __restrict__ offs,
                                                    int* __restrict__ ooff) {
    int g = blockIdx.x * 256 + threadIdx.x;   // grid sized exactly: RECN/256
    int b   = g / PER_B;
    int idx = g - b * PER_B;
    int n   = idx / NPTS;
    int p   = idx - n * NPTS;
    int py  = p / 5;
    int px  = p - py * 5;

    float cx = cand[((size_t)b * NN + n) * 2 + 0];
    float cy = cand[((size_t)b * NN + n) * 2 + 1];

    // exact torchvision roi_align sampling math (identical to prior kernel)
    float y = (cy - 2.0f) + ((float)py + 0.5f) * 0.8f;
    float x = (cx - 2.0f) + ((float)px + 0.5f) * 0.8f;
    bool valid = (y > -1.0f) && (y < (float)HH) && (x > -1.0f) && (x < (float)WW);
    y = fmaxf(y, 0.0f);
    x = fmaxf(x, 0.0f);
    int y0 = (int)y;
    int x0 = (int)x;
    bool yc = (y0 >= HH - 1);
    bool xc = (x0 >= WW - 1);
    if (yc) y0 = HH - 1;
    if (xc) x0 = WW - 1;
    int y1 = min(y0 + 1, HH - 1);
    int x1 = min(x0 + 1, WW - 1);
    float ly = yc ? 0.0f : y - (float)y0;
    float lx = xc ? 0.0f : x - (float)x0;
    float hy = 1.0f - ly, hx = 1.0f - lx;
    float vm = valid ? 1.0f : 0.0f;

    int r0 = y0 * WW, r1 = y1 * WW;
    // pre-shifted BYTE offsets into the fp16 plane: max (134*240+239)*2 = 64798
    offs[g] = make_ushort4((unsigned short)((r0 + x0) * 2),
                           (unsigned short)((r0 + x1) * 2),
                           (unsigned short)((r1 + x0) * 2),
                           (unsigned short)((r1 + x1) * 2));
    wts[g]  = make_float4(vm * hy * hx, vm * hy * lx, vm * ly * hx, vm * ly * lx);
    ooff[g] = n * (CCH * NPTS) + p;
}

// ---------------------------------------------------------------------------
// Phase 2: one block per (b, c). Plane staged fp16 in LDS (unchanged, proven
// read-side structure). Inner loop is now: 3 coalesced record loads (L2-hit,
// records reused by 256 channel-blocks) + 4 ds_read_u16 + mul/3fma + store.
// All sampling math / division / index math is gone from the hot loop.
// __launch_bounds__(1024, 8): cap VGPR at 64 so the 2-blocks/CU LDS limit
// stays the occupancy limit (32 waves/CU).
// ---------------------------------------------------------------------------
__global__ __launch_bounds__(1024, 8) void roi_plane_rec(const float* __restrict__ fm,
                                                         float* __restrict__ out,
                                                         const float4* __restrict__ wts,
                                                         const ushort4* __restrict__ offs,
                                                         const int* __restrict__ ooff) {
    __shared__ __half plane[HWP];   // 64,800 bytes

    int blk = blockIdx.x;           // 0..2047
    int c   = blk & (CCH - 1);
    int b   = blk >> 8;
    int t   = threadIdx.x;          // 0..1023

    // ---- stage plane (b,c) into LDS as fp16, float4-coalesced ----
    const float4* src = (const float4*)(fm + ((size_t)b * CCH + c) * HWP);
#pragma unroll
    for (int j = 0; j < 8; j++) {
        int e = j * 1024 + t;
        if (e < NV4) {
            float4 v = src[e];
            __half2* d = (__half2*)(plane + e * 4);   // 8B-aligned
            d[0] = __half2(__float2half(v.x), __float2half(v.y));
            d[1] = __half2(__float2half(v.z), __float2half(v.w));
        }
    }
    __syncthreads();

    const float4*  wb  = wts  + (size_t)b * PER_B;
    const ushort4* ob4 = offs + (size_t)b * PER_B;
    const int*     oob = ooff + (size_t)b * PER_B;
    float* obase = out + (size_t)b * NN * (CCH * NPTS) + c * NPTS;
    const char* pl = (const char*)plane;

#pragma unroll 5
    for (int k = 0; k < NPTS; k++) {
        int idx = k * 1024 + t;      // < 25600 exactly
        ushort4 o = ob4[idx];
        float4  w = wb[idx];
        int    oo = oob[idx];
        float v00 = __half2float(*(const __half*)(pl + o.x));
        float v01 = __half2float(*(const __half*)(pl + o.y));
        float v10 = __half2float(*(const __half*)(pl + o.z));
        float v11 = __half2float(*(const __half*)(pl + o.w));
        obase[oo] = w.x * v00 + w.y * v01 + w.z * v10 + w.w * v11;
    }
}

// ---------------------------------------------------------------------------
// Fallback (previous kernel, verified): used only if workspace is too small.
// ---------------------------------------------------------------------------
__global__ __launch_bounds__(1024) void roi_plane_kernel(const float* __restrict__ fm,
                                                         const float* __restrict__ cand,
                                                         float* __restrict__ out) {
    __shared__ __half plane[HWP];

    int blk = blockIdx.x;
    int c   = blk & (CCH - 1);
    int b   = blk >> 8;
    int t   = threadIdx.x;

    const float4* src = (const float4*)(fm + ((size_t)b * CCH + c) * HWP);
#pragma unroll
    for (int j = 0; j < 8; j++) {
        int e = j * 1024 + t;
        if (e < NV4) {
            float4 v = src[e];
            __half2* d = (__half2*)(plane + e * 4);
            d[0] = __half2(__float2half(v.x), __float2half(v.y));
            d[1] = __half2(__float2half(v.z), __float2half(v.w));
        }
    }
    __syncthreads();

    const float* cb = cand + (size_t)b * NN * 2;
    float* ob = out + (size_t)b * NN * (CCH * NPTS) + c * NPTS;

    for (int k = 0; k < NPTS; k++) {
        int idx = k * 1024 + t;
        int n   = idx / 25;
        int p   = idx - n * 25;
        int py  = p / 5;
        int px  = p - py * 5;

        float cx = cb[n * 2 + 0];
        float cy = cb[n * 2 + 1];

        float y = (cy - 2.0f) + ((float)py + 0.5f) * 0.8f;
        float x = (cx - 2.0f) + ((float)px + 0.5f) * 0.8f;
        bool valid = (y > -1.0f) && (y < (float)HH) && (x > -1.0f) && (x < (float)WW);
        y = fmaxf(y, 0.0f);
        x = fmaxf(x, 0.0f);
        int y0 = (int)y;
        int x0 = (int)x;
        bool yc = (y0 >= HH - 1);
        bool xc = (x0 >= WW - 1);
        if (yc) y0 = HH - 1;
        if (xc) x0 = WW - 1;
        int y1 = min(y0 + 1, HH - 1);
        int x1 = min(x0 + 1, WW - 1);
        float ly = yc ? 0.0f : y - (float)y0;
        float lx = xc ? 0.0f : x - (float)x0;
        float hy = 1.0f - ly, hx = 1.0f - lx;
        float vm = valid ? 1.0f : 0.0f;

        int r0 = y0 * WW, r1 = y1 * WW;
        float v00 = __half2float(plane[r0 + x0]);
        float v01 = __half2float(plane[r0 + x1]);
        float v10 = __half2float(plane[r1 + x0]);
        float v11 = __half2float(plane[r1 + x1]);

        float r = (hy * hx * v00 + hy * lx * v01 + ly * hx * v10 + ly * lx * v11) * vm;
        ob[(size_t)n * (CCH * NPTS) + p] = r;
    }
}

extern "C" void kernel_launch(void* const* d_in, const int* in_sizes, int n_in,
                              void* d_out, int out_size, void* d_ws, size_t ws_size,
                              hipStream_t stream) {
    const float* fm   = (const float*)d_in[0];
    const float* cand = (const float*)d_in[1];
    float* out        = (float*)d_out;

    if (d_ws != nullptr && ws_size >= WS_NEED) {
        float4*  wts  = (float4*)((char*)d_ws + WS_WTS);
        ushort4* offs = (ushort4*)((char*)d_ws + WS_OFFS);
        int*     ooff = (int*)((char*)d_ws + WS_OOFF);
        make_records<<<RECN / 256, 256, 0, stream>>>(cand, wts, offs, ooff);
        roi_plane_rec<<<NB * CCH, 1024, 0, stream>>>(fm, out, wts, offs, ooff);
    } else {
        roi_plane_kernel<<<NB * CCH, 1024, 0, stream>>>(fm, cand, out);
    }
}

// Round 2
// 507.070 us; speedup vs baseline: 1.0230x; 1.0230x over previous
//
#include <hip/hip_runtime.h>
#include <hip/hip_fp16.h>

#define ROI 5
#define NPTS 25          // 5*5
#define CCH 256
#define HH 135
#define WW 240
#define HWP (HH * WW)    // 32400
#define NV4 (HWP / 4)    // 8100 float4 per plane
#define NB 8
#define NN 1024
#define PER_B (NN * NPTS)        // 25600 records per batch
#define RECN (NB * PER_B)        // 204800 records total
#define RECPAD 1024              // prefetch overrun pad (last batch, k=24)

// workspace layout:
//   float4  wts [RECN+RECPAD] @ 0        (3,293,184 B)
//   ushort4 offs[RECN+RECPAD] @ WS_OFFS  (1,646,592 B)  -- BYTE offsets into fp16 plane
#define WS_WTS  0
#define WS_OFFS ((RECN + RECPAD) * 16)
#define WS_NEED (size_t)(WS_OFFS + (RECN + RECPAD) * 8)   // 4,939,776 B

// ---------------------------------------------------------------------------
// Phase 1: one record per (b, n, p). Sampling math done ONCE instead of
// once-per-channel. Pad region is written with safe zeros.
// ---------------------------------------------------------------------------
__global__ __launch_bounds__(256) void make_records(const float* __restrict__ cand,
                                                    float4* __restrict__ wts,
                                                    ushort4* __restrict__ offs) {
    int g = blockIdx.x * 256 + threadIdx.x;   // grid = (RECN+RECPAD)/256
    if (g >= RECN) {                          // pad: valid-but-unused records
        if (g < RECN + RECPAD) {
            wts[g]  = make_float4(0.f, 0.f, 0.f, 0.f);
            offs[g] = make_ushort4(0, 0, 0, 0);
        }
        return;
    }
    int b   = g / PER_B;
    int idx = g - b * PER_B;
    int n   = idx / NPTS;
    int p   = idx - n * NPTS;
    int py  = p / 5;
    int px  = p - py * 5;

    float cx = cand[((size_t)b * NN + n) * 2 + 0];
    float cy = cand[((size_t)b * NN + n) * 2 + 1];

    // exact torchvision roi_align sampling math (identical to verified kernel)
    float y = (cy - 2.0f) + ((float)py + 0.5f) * 0.8f;
    float x = (cx - 2.0f) + ((float)px + 0.5f) * 0.8f;
    bool valid = (y > -1.0f) && (y < (float)HH) && (x > -1.0f) && (x < (float)WW);
    y = fmaxf(y, 0.0f);
    x = fmaxf(x, 0.0f);
    int y0 = (int)y;
    int x0 = (int)x;
    bool yc = (y0 >= HH - 1);
    bool xc = (x0 >= WW - 1);
    if (yc) y0 = HH - 1;
    if (xc) x0 = WW - 1;
    int y1 = min(y0 + 1, HH - 1);
    int x1 = min(x0 + 1, WW - 1);
    float ly = yc ? 0.0f : y - (float)y0;
    float lx = xc ? 0.0f : x - (float)x0;
    float hy = 1.0f - ly, hx = 1.0f - lx;
    float vm = valid ? 1.0f : 0.0f;

    int r0 = y0 * WW, r1 = y1 * WW;
    // pre-shifted BYTE offsets into the fp16 plane: max (134*240+239)*2 = 64798
    offs[g] = make_ushort4((unsigned short)((r0 + x0) * 2),
                           (unsigned short)((r0 + x1) * 2),
                           (unsigned short)((r1 + x0) * 2),
                           (unsigned short)((r1 + x1) * 2));
    wts[g]  = make_float4(vm * hy * hx, vm * hy * lx, vm * ly * hx, vm * ly * lx);
}

// ---------------------------------------------------------------------------
// Phase 2: one block per (b, c). Plane staged fp16 in LDS (proven structure).
// Inner loop: manual depth-1 prefetch of next iteration's record hides the
// L2 load latency under this iteration's LDS gather + FMA + store.
// Output offset computed arithmetically: n = idx/25 via exact magic multiply,
// oo = n*6400 + p = idx + 6375*n  (trades an idle-VALU op for a dependent
// global load -- VALU was only 13% busy).
// ---------------------------------------------------------------------------
__global__ __launch_bounds__(1024, 8) void roi_plane_rec(const float* __restrict__ fm,
                                                         float* __restrict__ out,
                                                         const float4* __restrict__ wts,
                                                         const ushort4* __restrict__ offs) {
    __shared__ __half plane[HWP];   // 64,800 bytes

    int blk = blockIdx.x;           // 0..2047
    int c   = blk & (CCH - 1);
    int b   = blk >> 8;
    int t   = threadIdx.x;          // 0..1023

    // ---- stage plane (b,c) into LDS as fp16, float4-coalesced ----
    const float4* src = (const float4*)(fm + ((size_t)b * CCH + c) * HWP);
#pragma unroll
    for (int j = 0; j < 8; j++) {
        int e = j * 1024 + t;
        if (e < NV4) {
            float4 v = src[e];
            __half2* d = (__half2*)(plane + e * 4);   // 8B-aligned
            d[0] = __half2(__float2half(v.x), __float2half(v.y));
            d[1] = __half2(__float2half(v.z), __float2half(v.w));
        }
    }
    __syncthreads();

    const float4*  wb  = wts  + (size_t)b * PER_B;
    const ushort4* ob4 = offs + (size_t)b * PER_B;
    float* obase = out + (size_t)b * NN * (CCH * NPTS) + c * NPTS;
    const char* pl = (const char*)plane;

    int idx = t;
    ushort4 o = ob4[idx];
    float4  w = wb[idx];
#pragma unroll 1
    for (int k = 0; k < NPTS; k++) {
        // prefetch next record (pad region makes k=24 overrun safe)
        ushort4 o2 = ob4[idx + 1024];
        float4  w2 = wb[idx + 1024];

        float v00 = __half2float(*(const __half*)(pl + o.x));
        float v01 = __half2float(*(const __half*)(pl + o.y));
        float v10 = __half2float(*(const __half*)(pl + o.z));
        float v11 = __half2float(*(const __half*)(pl + o.w));

        int n  = (idx * 5243) >> 17;      // exact idx/25 for idx < 25600
        int oo = idx + n * 6375;          // n*6400 + (idx - 25n)

        obase[oo] = w.x * v00 + w.y * v01 + w.z * v10 + w.w * v11;

        idx += 1024;
        o = o2;
        w = w2;
    }
}

// ---------------------------------------------------------------------------
// Fallback (round-0 verified kernel): used only if workspace is too small.
// ---------------------------------------------------------------------------
__global__ __launch_bounds__(1024) void roi_plane_kernel(const float* __restrict__ fm,
                                                         const float* __restrict__ cand,
                                                         float* __restrict__ out) {
    __shared__ __half plane[HWP];

    int blk = blockIdx.x;
    int c   = blk & (CCH - 1);
    int b   = blk >> 8;
    int t   = threadIdx.x;

    const float4* src = (const float4*)(fm + ((size_t)b * CCH + c) * HWP);
#pragma unroll
    for (int j = 0; j < 8; j++) {
        int e = j * 1024 + t;
        if (e < NV4) {
            float4 v = src[e];
            __half2* d = (__half2*)(plane + e * 4);
            d[0] = __half2(__float2half(v.x), __float2half(v.y));
            d[1] = __half2(__float2half(v.z), __float2half(v.w));
        }
    }
    __syncthreads();

    const float* cb = cand + (size_t)b * NN * 2;
    float* ob = out + (size_t)b * NN * (CCH * NPTS) + c * NPTS;

    for (int k = 0; k < NPTS; k++) {
        int idx = k * 1024 + t;
        int n   = idx / 25;
        int p   = idx - n * 25;
        int py  = p / 5;
        int px  = p - py * 5;

        float cx = cb[n * 2 + 0];
        float cy = cb[n * 2 + 1];

        float y = (cy - 2.0f) + ((float)py + 0.5f) * 0.8f;
        float x = (cx - 2.0f) + ((float)px + 0.5f) * 0.8f;
        bool valid = (y > -1.0f) && (y < (float)HH) && (x > -1.0f) && (x < (float)WW);
        y = fmaxf(y, 0.0f);
        x = fmaxf(x, 0.0f);
        int y0 = (int)y;
        int x0 = (int)x;
        bool yc = (y0 >= HH - 1);
        bool xc = (x0 >= WW - 1);
        if (yc) y0 = HH - 1;
        if (xc) x0 = WW - 1;
        int y1 = min(y0 + 1, HH - 1);
        int x1 = min(x0 + 1, WW - 1);
        float ly = yc ? 0.0f : y - (float)y0;
        float lx = xc ? 0.0f : x - (float)x0;
        float hy = 1.0f - ly, hx = 1.0f - lx;
        float vm = valid ? 1.0f : 0.0f;

        int r0 = y0 * WW, r1 = y1 * WW;
        float v00 = __half2float(plane[r0 + x0]);
        float v01 = __half2float(plane[r0 + x1]);
        float v10 = __half2float(plane[r1 + x0]);
        float v11 = __half2float(plane[r1 + x1]);

        float r = (hy * hx * v00 + hy * lx * v01 + ly * hx * v10 + ly * lx * v11) * vm;
        ob[(size_t)n * (CCH * NPTS) + p] = r;
    }
}

extern "C" void kernel_launch(void* const* d_in, const int* in_sizes, int n_in,
                              void* d_out, int out_size, void* d_ws, size_t ws_size,
                              hipStream_t stream) {
    const float* fm   = (const float*)d_in[0];
    const float* cand = (const float*)d_in[1];
    float* out        = (float*)d_out;

    if (d_ws != nullptr && ws_size >= WS_NEED) {
        float4*  wts  = (float4*)((char*)d_ws + WS_WTS);
        ushort4* offs = (ushort4*)((char*)d_ws + WS_OFFS);
        make_records<<<(RECN + RECPAD) / 256, 256, 0, stream>>>(cand, wts, offs);
        roi_plane_rec<<<NB * CCH, 1024, 0, stream>>>(fm, out, wts, offs);
    } else {
        roi_plane_kernel<<<NB * CCH, 1024, 0, stream>>>(fm, cand, out);
    }
}

// Round 3
// 496.821 us; speedup vs baseline: 1.0441x; 1.0206x over previous
//
#include <hip/hip_runtime.h>
#include <hip/hip_fp16.h>

#define ROI 5
#define NPTS 25          // 5*5
#define CCH 256
#define HH 135
#define WW 240
#define HWP (HH * WW)    // 32400
#define NV4 (HWP / 4)    // 8100 float4 per plane
#define NB 8
#define NN 1024

// ---------------------------------------------------------------------------
// One block per (b, c); 135x240 plane staged as fp16 in LDS (64,800 B ->
// 2 blocks/CU, 32 waves/CU). Lesson from rounds 1-2: the inner loop is
// LATENCY-bound, not VALU-bound. Precomputed records (L2-resident) made it
// slower than inline math (candidates are 8 KB/batch -> L1-resident).
// So: inline math + explicit 2-point ILP per iteration. Point B's ~60 VALU
// ops and 4 ds_reads overlap point A's LDS-gather latency; per-point exposed
// latency is halved and the (6x-underutilized) VALU provides the cover.
// ---------------------------------------------------------------------------

struct Pt { int o00, o01, o10, o11; float w00, w01, w10, w11; int oo; };

__device__ __forceinline__ Pt prep(const float2* __restrict__ cb2, int idx) {
    Pt r;
    int n  = (idx * 5243) >> 17;      // exact idx/25 for idx < 25600
    int p  = idx - n * 25;
    int py = (p * 205) >> 10;         // exact p/5 for p < 25
    int px = p - py * 5;

    float2 cc = cb2[n];               // L1-resident (8 KB per batch)

    // exact torchvision roi_align sampling math (identical to r0-verified)
    float y = (cc.y - 2.0f) + ((float)py + 0.5f) * 0.8f;
    float x = (cc.x - 2.0f) + ((float)px + 0.5f) * 0.8f;
    bool valid = (y > -1.0f) && (y < (float)HH) && (x > -1.0f) && (x < (float)WW);
    y = fmaxf(y, 0.0f);
    x = fmaxf(x, 0.0f);
    int y0 = (int)y;                  // y >= 0, trunc == floor
    int x0 = (int)x;
    bool yc = (y0 >= HH - 1);
    bool xc = (x0 >= WW - 1);
    if (yc) y0 = HH - 1;
    if (xc) x0 = WW - 1;
    int y1 = min(y0 + 1, HH - 1);
    int x1 = min(x0 + 1, WW - 1);
    float ly = yc ? 0.0f : y - (float)y0;
    float lx = xc ? 0.0f : x - (float)x0;
    float hy = 1.0f - ly, hx = 1.0f - lx;
    float vm = valid ? 1.0f : 0.0f;   // folded into weights: exact (x1.0/x0.0)

    int r0 = y0 * WW, r1 = y1 * WW;
    r.o00 = r0 + x0; r.o01 = r0 + x1; r.o10 = r1 + x0; r.o11 = r1 + x1;
    float vhy = vm * hy, vly = vm * ly;
    r.w00 = vhy * hx; r.w01 = vhy * lx; r.w10 = vly * hx; r.w11 = vly * lx;
    r.oo = idx + n * 6375;            // n*6400 + p
    return r;
}

__global__ __launch_bounds__(1024, 8) void roi_plane_ilp2(const float* __restrict__ fm,
                                                          const float* __restrict__ cand,
                                                          float* __restrict__ out) {
    __shared__ __half plane[HWP];   // 64,800 bytes

    int blk = blockIdx.x;           // 0..2047
    int c   = blk & (CCH - 1);
    int b   = blk >> 8;
    int t   = threadIdx.x;          // 0..1023

    // ---- stage plane (b,c) into LDS as fp16, 4 float4 in flight ----
    const float4* src = (const float4*)(fm + ((size_t)b * CCH + c) * HWP);
    {
        // j=0..6: e = j*1024+t <= 7167 < 8100, no bounds check needed
        float4 v0 = src[t];
        float4 v1 = src[1024 + t];
        float4 v2 = src[2048 + t];
        float4 v3 = src[3072 + t];
        __half2* d;
        d = (__half2*)(plane + (t) * 4);
        d[0] = __half2(__float2half(v0.x), __float2half(v0.y));
        d[1] = __half2(__float2half(v0.z), __float2half(v0.w));
        d = (__half2*)(plane + (1024 + t) * 4);
        d[0] = __half2(__float2half(v1.x), __float2half(v1.y));
        d[1] = __half2(__float2half(v1.z), __float2half(v1.w));
        d = (__half2*)(plane + (2048 + t) * 4);
        d[0] = __half2(__float2half(v2.x), __float2half(v2.y));
        d[1] = __half2(__float2half(v2.z), __float2half(v2.w));
        d = (__half2*)(plane + (3072 + t) * 4);
        d[0] = __half2(__float2half(v3.x), __float2half(v3.y));
        d[1] = __half2(__float2half(v3.z), __float2half(v3.w));

        float4 v4 = src[4096 + t];
        float4 v5 = src[5120 + t];
        float4 v6 = src[6144 + t];
        bool last = (t < NV4 - 7168);   // t < 932
        float4 v7 = last ? src[7168 + t] : make_float4(0.f, 0.f, 0.f, 0.f);
        d = (__half2*)(plane + (4096 + t) * 4);
        d[0] = __half2(__float2half(v4.x), __float2half(v4.y));
        d[1] = __half2(__float2half(v4.z), __float2half(v4.w));
        d = (__half2*)(plane + (5120 + t) * 4);
        d[0] = __half2(__float2half(v5.x), __float2half(v5.y));
        d[1] = __half2(__float2half(v5.z), __float2half(v5.w));
        d = (__half2*)(plane + (6144 + t) * 4);
        d[0] = __half2(__float2half(v6.x), __float2half(v6.y));
        d[1] = __half2(__float2half(v6.z), __float2half(v6.w));
        if (last) {
            d = (__half2*)(plane + (7168 + t) * 4);
            d[0] = __half2(__float2half(v7.x), __float2half(v7.y));
            d[1] = __half2(__float2half(v7.z), __float2half(v7.w));
        }
    }
    __syncthreads();

    const float2* cb2 = (const float2*)(cand + (size_t)b * NN * 2);
    float* obase = out + (size_t)b * NN * (CCH * NPTS) + c * NPTS;

    // 25600 points: 12 double-iterations (idx and idx+12288) + 1 tail
#pragma unroll 1
    for (int k = 0; k < 12; k++) {
        int ia = k * 1024 + t;
        Pt A = prep(cb2, ia);
        Pt B = prep(cb2, ia + 12288);

        // issue all 8 gathers before any use; B covers A's latency
        float a00 = __half2float(plane[A.o00]);
        float a01 = __half2float(plane[A.o01]);
        float a10 = __half2float(plane[A.o10]);
        float a11 = __half2float(plane[A.o11]);
        float b00 = __half2float(plane[B.o00]);
        float b01 = __half2float(plane[B.o01]);
        float b10 = __half2float(plane[B.o10]);
        float b11 = __half2float(plane[B.o11]);

        obase[A.oo] = A.w00 * a00 + A.w01 * a01 + A.w10 * a10 + A.w11 * a11;
        obase[B.oo] = B.w00 * b00 + B.w01 * b01 + B.w10 * b10 + B.w11 * b11;
    }
    {
        Pt A = prep(cb2, 24576 + t);
        float a00 = __half2float(plane[A.o00]);
        float a01 = __half2float(plane[A.o01]);
        float a10 = __half2float(plane[A.o10]);
        float a11 = __half2float(plane[A.o11]);
        obase[A.oo] = A.w00 * a00 + A.w01 * a01 + A.w10 * a10 + A.w11 * a11;
    }
}

extern "C" void kernel_launch(void* const* d_in, const int* in_sizes, int n_in,
                              void* d_out, int out_size, void* d_ws, size_t ws_size,
                              hipStream_t stream) {
    const float* fm   = (const float*)d_in[0];
    const float* cand = (const float*)d_in[1];
    float* out        = (float*)d_out;

    roi_plane_ilp2<<<NB * CCH, 1024, 0, stream>>>(fm, cand, out);
}